// Round 2
// baseline (444.690 us; speedup 1.0000x reference)
//
#include <hip/hip_runtime.h>
#include <math.h>

#define B_ 2
#define N_ 2048
#define E_ 1024
#define H_ 16
#define D_ 64
#define NE_ (B_*H_*N_*D_) // 4194304 elements per tensor

typedef unsigned short US;
typedef short s16x8 __attribute__((ext_vector_type(8)));
typedef float f32x4 __attribute__((ext_vector_type(4)));
#define MFMA16(a,b,c) __builtin_amdgcn_mfma_f32_16x16x32_bf16(a,b,c,0,0,0)

__device__ __forceinline__ float bf2f(US s){
  union{unsigned u; float f;} x; x.u = ((unsigned)s)<<16; return x.f;
}
__device__ __forceinline__ US f2bf(float f){
  union{float f; unsigned u;} x; x.f = f;
  unsigned r = x.u + 0x7fffu + ((x.u>>16)&1u);   // round-to-nearest-even
  return (US)(r>>16);
}

union U8 { US u[8]; uint4 v; };

// C = A @ W^T + bias.  A: [4096 x 1024], W: [1024 x 1024] fp32 row-major [out][in].
// MODE 0: A fp32, 3-term split MFMA; out0/out1 = hi/lo bf16 split, layout [B,H,N,D]  (Q, K)
// MODE 1: A fp32, 1-term;            out0 = bf16, layout [B,H,N,D]                   (V)
// MODE 2: A bf16, 1-term;            out0 = fp32, row-major [4096][1024]             (final)
#define LSTR 40   // 32 + 8 pad: row stride 80B = 20 dwords -> 2-way max (free)
template<int MODE>
__global__ __launch_bounds__(256) void gemm_bt(
    const void* __restrict__ Av, const float* __restrict__ W, const float* __restrict__ bias,
    void* __restrict__ out0, US* __restrict__ out1)
{
  __shared__ __align__(16) US Ah[64*LSTR];
  __shared__ __align__(16) US Wh[64*LSTR];
  __shared__ __align__(16) US Al[(MODE==0)?64*LSTR:8];
  __shared__ __align__(16) US Wl[(MODE==0)?64*LSTR:8];
  const int t = threadIdx.x;
  const int gm0 = blockIdx.y*64, gn0 = blockIdx.x*64;
  const int w = t>>6, lane = t&63;
  const int wr = w>>1, wc = w&1;           // 2x2 waves, each 32x32
  const int q = lane>>4, c = lane&15;
  const int lm = t>>2, kg = (t&3)*8;       // staging: 4 thr/row, 8 elems each
  const int ko = q*8;                      // frag k-chunk within BK=32
  f32x4 acc[2][2] = {};
  for (int kb = 0; kb < 1024; kb += 32) {
    // --- stage A ---
    if (MODE == 2) {
      const US* A16 = (const US*)Av;
      *(uint4*)&Ah[lm*LSTR+kg] = *(const uint4*)&A16[(gm0+lm)*1024 + kb + kg];
    } else {
      const float* Af = (const float*)Av;
      float f[8];
      *(float4*)&f[0] = *(const float4*)&Af[(gm0+lm)*1024 + kb + kg];
      *(float4*)&f[4] = *(const float4*)&Af[(gm0+lm)*1024 + kb + kg + 4];
      U8 h, l;
      #pragma unroll
      for (int j=0;j<8;++j){
        h.u[j] = f2bf(f[j]);
        if (MODE==0) l.u[j] = f2bf(f[j] - bf2f(h.u[j]));
      }
      *(uint4*)&Ah[lm*LSTR+kg] = h.v;
      if (MODE==0) *(uint4*)&Al[lm*LSTR+kg] = l.v;
    }
    // --- stage W ---
    {
      float f[8];
      *(float4*)&f[0] = *(const float4*)&W[(gn0+lm)*1024 + kb + kg];
      *(float4*)&f[4] = *(const float4*)&W[(gn0+lm)*1024 + kb + kg + 4];
      U8 h, l;
      #pragma unroll
      for (int j=0;j<8;++j){
        h.u[j] = f2bf(f[j]);
        if (MODE==0) l.u[j] = f2bf(f[j] - bf2f(h.u[j]));
      }
      *(uint4*)&Wh[lm*LSTR+kg] = h.v;
      if (MODE==0) *(uint4*)&Wl[lm*LSTR+kg] = l.v;
    }
    __syncthreads();
    s16x8 a0 = *(const s16x8*)&Ah[(wr*32+c)*LSTR + ko];
    s16x8 a1 = *(const s16x8*)&Ah[(wr*32+16+c)*LSTR + ko];
    s16x8 b0 = *(const s16x8*)&Wh[(wc*32+c)*LSTR + ko];
    s16x8 b1 = *(const s16x8*)&Wh[(wc*32+16+c)*LSTR + ko];
    acc[0][0] = MFMA16(a0,b0,acc[0][0]);
    acc[0][1] = MFMA16(a0,b1,acc[0][1]);
    acc[1][0] = MFMA16(a1,b0,acc[1][0]);
    acc[1][1] = MFMA16(a1,b1,acc[1][1]);
    if (MODE==0) {
      s16x8 a0l = *(const s16x8*)&Al[(wr*32+c)*LSTR + ko];
      s16x8 a1l = *(const s16x8*)&Al[(wr*32+16+c)*LSTR + ko];
      s16x8 b0l = *(const s16x8*)&Wl[(wc*32+c)*LSTR + ko];
      s16x8 b1l = *(const s16x8*)&Wl[(wc*32+16+c)*LSTR + ko];
      acc[0][0] = MFMA16(a0,b0l,acc[0][0]);
      acc[0][1] = MFMA16(a0,b1l,acc[0][1]);
      acc[1][0] = MFMA16(a1,b0l,acc[1][0]);
      acc[1][1] = MFMA16(a1,b1l,acc[1][1]);
      acc[0][0] = MFMA16(a0l,b0,acc[0][0]);
      acc[0][1] = MFMA16(a0l,b1,acc[0][1]);
      acc[1][0] = MFMA16(a1l,b0,acc[1][0]);
      acc[1][1] = MFMA16(a1l,b1,acc[1][1]);
    }
    __syncthreads();
  }
  #pragma unroll
  for (int f=0; f<2; ++f)
  #pragma unroll
  for (int g=0; g<2; ++g) {
    int col = gn0 + wc*32 + g*16 + c;
    float bv = bias[col];
    #pragma unroll
    for (int r=0; r<4; ++r) {
      int row = gm0 + wr*32 + f*16 + q*4 + r;   // C layout: row=(lane>>4)*4+reg, col=lane&15
      float v = acc[f][g][r] + bv;
      if (MODE == 2) {
        ((float*)out0)[row*1024 + col] = v;
      } else {
        int b = row>>11, n = row & (N_-1), hh = col>>6, d = col & 63;
        int idx = ((b*H_+hh)*N_+n)*D_ + d;
        US hi = f2bf(v);
        ((US*)out0)[idx] = hi;
        if (MODE == 0) out1[idx] = f2bf(v - bf2f(hi));
      }
    }
  }
}

// Flash-style attention: one block = one (b,h) x 64 q-rows; wave w owns q-rows 16w..16w+15.
// Split-bf16 QK^T (hi*hi + hi*lo + lo*hi), online softmax, PV via LDS P-transpose.
#define ASTR 72   // 64 + 8 pad: row stride 144B = 36 dwords -> 2-way max (free)
__global__ __launch_bounds__(256) void attn(
    const US* __restrict__ Qhi, const US* __restrict__ Qlo,
    const US* __restrict__ Khi, const US* __restrict__ Klo,
    const US* __restrict__ Vb,  US* __restrict__ Hout)
{
  __shared__ __align__(16) US sQh[64*ASTR], sQl[64*ASTR];
  __shared__ __align__(16) US sKh[64*ASTR], sKl[64*ASTR];
  __shared__ __align__(16) US sVt[64*ASTR];     // transposed V tile [d][m]
  __shared__ __align__(16) US sP[4][16*ASTR];   // per-wave P buffer
  const int t = threadIdx.x;
  const int w = t>>6, lane = t&63, q = lane>>4, c = lane&15;
  const int bh = blockIdx.y;          // b*16 + h
  const int n0 = blockIdx.x*64;
  const int base = bh * (N_*D_);
  const US* Qh = Qhi + base; const US* Ql = Qlo + base;
  const US* Kh = Khi + base; const US* Kl = Klo + base;
  const US* Vv = Vb  + base;

  const int sr = t>>3, sk = (t&7)*8;  // staging: 8 thr/row, 8 bf16 each
  #pragma unroll
  for (int p=0;p<2;p++){
    int m = sr + 32*p;
    *(uint4*)&sQh[m*ASTR+sk] = *(const uint4*)&Qh[(n0+m)*D_ + sk];
    *(uint4*)&sQl[m*ASTR+sk] = *(const uint4*)&Ql[(n0+m)*D_ + sk];
  }

  float mi[4], li[4];
  f32x4 o[4];
  #pragma unroll
  for (int r=0;r<4;++r){ mi[r] = -INFINITY; li[r] = 0.f; f32x4 z = {}; o[r] = z; }

  const int ar = w*16 + c;            // this wave's A rows in sQ
  const int pr = t>>3;                // V-transpose pair index 0..31
  const int d0 = (t&7)*8;

  for (int mt=0; mt<32; ++mt) {
    const int m0 = mt*64;
    #pragma unroll
    for (int p=0;p<2;p++){
      int m = sr + 32*p;
      *(uint4*)&sKh[m*ASTR+sk] = *(const uint4*)&Kh[(m0+m)*D_ + sk];
      *(uint4*)&sKl[m*ASTR+sk] = *(const uint4*)&Kl[(m0+m)*D_ + sk];
    }
    { // stage V transposed: sVt[d][m], pack 2 m's per b32 write
      uint4 va = *(const uint4*)&Vv[(m0+2*pr)*D_ + d0];
      uint4 vb = *(const uint4*)&Vv[(m0+2*pr+1)*D_ + d0];
      const US* pa = (const US*)&va; const US* pb = (const US*)&vb;
      int rot = (d0>>3)&7;            // stagger to avoid 8-way bank aliasing
      #pragma unroll
      for (int jj=0;jj<8;++jj){
        int j = (jj + rot)&7;
        unsigned pack = (unsigned)pa[j] | ((unsigned)pb[j]<<16);
        *(unsigned*)&sVt[(d0+j)*ASTR + 2*pr] = pack;
      }
    }
    __syncthreads();

    // S tile: this wave's 16 q-rows x 64 m-cols, split-bf16
    s16x8 ah0 = *(const s16x8*)&sQh[ar*ASTR + q*8];
    s16x8 ah1 = *(const s16x8*)&sQh[ar*ASTR + 32 + q*8];
    s16x8 al0 = *(const s16x8*)&sQl[ar*ASTR + q*8];
    s16x8 al1 = *(const s16x8*)&sQl[ar*ASTR + 32 + q*8];
    f32x4 s[4];
    #pragma unroll
    for (int j=0;j<4;++j){
      int br = j*16 + c;
      s16x8 bh0 = *(const s16x8*)&sKh[br*ASTR + q*8];
      s16x8 bh1 = *(const s16x8*)&sKh[br*ASTR + 32 + q*8];
      s16x8 bl0 = *(const s16x8*)&sKl[br*ASTR + q*8];
      s16x8 bl1 = *(const s16x8*)&sKl[br*ASTR + 32 + q*8];
      f32x4 sv = {};
      sv = MFMA16(ah0,bh0,sv);
      sv = MFMA16(ah1,bh1,sv);
      sv = MFMA16(ah0,bl0,sv);
      sv = MFMA16(ah1,bl1,sv);
      sv = MFMA16(al0,bh0,sv);
      sv = MFMA16(al1,bh1,sv);
      s[j] = sv;
    }
    #pragma unroll
    for (int j=0;j<4;++j) s[j] *= 8.0f;   // logits = dot * sqrt(D)

    // online softmax: rows live in quads (row = q*4+r), reduce over 16 lanes
    float alpha[4];
    #pragma unroll
    for (int r=0;r<4;++r){
      float v = fmaxf(fmaxf(s[0][r],s[1][r]), fmaxf(s[2][r],s[3][r]));
      v = fmaxf(v, __shfl_xor(v,1));
      v = fmaxf(v, __shfl_xor(v,2));
      v = fmaxf(v, __shfl_xor(v,4));
      v = fmaxf(v, __shfl_xor(v,8));
      float mnew = fmaxf(mi[r], v);
      alpha[r] = __expf(mi[r]-mnew);
      mi[r] = mnew;
      float ps = 0.f;
      #pragma unroll
      for (int j=0;j<4;++j){
        float p = __expf(s[j][r]-mnew);
        s[j][r] = p;
        ps += p;
      }
      ps += __shfl_xor(ps,1);
      ps += __shfl_xor(ps,2);
      ps += __shfl_xor(ps,4);
      ps += __shfl_xor(ps,8);
      li[r] = li[r]*alpha[r] + ps;
    }
    #pragma unroll
    for (int dt=0;dt<4;++dt){
      #pragma unroll
      for (int r=0;r<4;++r) o[dt][r] *= alpha[r];
    }
    // P: C-layout regs -> LDS -> A-layout frags (per-wave buffer, no block sync needed)
    #pragma unroll
    for (int j=0;j<4;++j)
      #pragma unroll
      for (int r=0;r<4;++r)
        sP[w][(q*4+r)*ASTR + j*16 + c] = f2bf(s[j][r]);
    s16x8 pa0 = *(const s16x8*)&sP[w][c*ASTR + q*8];
    s16x8 pa1 = *(const s16x8*)&sP[w][c*ASTR + 32 + q*8];
    #pragma unroll
    for (int dt=0;dt<4;++dt){
      s16x8 vb0 = *(const s16x8*)&sVt[(dt*16+c)*ASTR + q*8];
      s16x8 vb1 = *(const s16x8*)&sVt[(dt*16+c)*ASTR + 32 + q*8];
      o[dt] = MFMA16(pa0, vb0, o[dt]);
      o[dt] = MFMA16(pa1, vb1, o[dt]);
    }
    __syncthreads();
  }
  const int b = bh>>4, hh = bh&15;
  #pragma unroll
  for (int dt=0;dt<4;++dt){
    #pragma unroll
    for (int r=0;r<4;++r){
      int n = n0 + w*16 + q*4 + r;
      int d = dt*16 + c;
      float val = o[dt][r] / li[r];
      Hout[((b*N_+n)*H_+hh)*D_ + d] = f2bf(val);   // [B,N,E] row-major, bf16
    }
  }
}

extern "C" void kernel_launch(void* const* d_in, const int* in_sizes, int n_in,
                              void* d_out, int out_size, void* d_ws, size_t ws_size,
                              hipStream_t stream)
{
  const float* x  = (const float*)d_in[0];
  const float* Wq = (const float*)d_in[1];
  const float* bq = (const float*)d_in[2];
  const float* Wk = (const float*)d_in[3];
  const float* bk = (const float*)d_in[4];
  const float* Wv = (const float*)d_in[5];
  const float* bv = (const float*)d_in[6];
  const float* Wo = (const float*)d_in[7];
  const float* bo = (const float*)d_in[8];
  US* ws  = (US*)d_ws;
  US* Qhi = ws;
  US* Qlo = ws + (size_t)1*NE_;
  US* Khi = ws + (size_t)2*NE_;
  US* Klo = ws + (size_t)3*NE_;
  US* Vb  = ws + (size_t)4*NE_;
  US* Hb  = ws + (size_t)5*NE_;   // total 6*NE_*2 = 50.3 MB of d_ws

  dim3 gg(16, 64), bb(256, 1, 1);
  gemm_bt<0><<<gg, bb, 0, stream>>>(x, Wq, bq, Qhi, Qlo);
  gemm_bt<0><<<gg, bb, 0, stream>>>(x, Wk, bk, Khi, Klo);
  gemm_bt<1><<<gg, bb, 0, stream>>>(x, Wv, bv, Vb, nullptr);
  attn<<<dim3(32,32,1), bb, 0, stream>>>(Qhi, Qlo, Khi, Klo, Vb, Hb);
  gemm_bt<2><<<gg, bb, 0, stream>>>(Hb, Wo, bo, d_out, nullptr);
}

// Round 3
// 356.976 us; speedup vs baseline: 1.2457x; 1.2457x over previous
//
#include <hip/hip_runtime.h>
#include <math.h>

#define B_ 2
#define N_ 2048
#define E_ 1024
#define H_ 16
#define D_ 64
#define NE_ (B_*H_*N_*D_) // 4194304 elements per tensor

typedef unsigned short US;
typedef _Float16 h16x8 __attribute__((ext_vector_type(8)));
typedef float f32x4 __attribute__((ext_vector_type(4)));
#define MFMA16F(a,b,c) __builtin_amdgcn_mfma_f32_16x16x32_f16(a,b,c,0,0,0)

union HU { _Float16 h; US u; };
__device__ __forceinline__ US f2h(float f){ HU x; x.h = (_Float16)f; return x.u; }
__device__ __forceinline__ float h2f(US u){ HU x; x.u = u; return (float)x.h; }

union U8 { US u[8]; uint4 v; };

// ---- converts: fp32 -> fp16 (hi [+ residual lo]) ----
__global__ __launch_bounds__(256) void conv_x(const float* __restrict__ x,
                                              US* __restrict__ hi, US* __restrict__ lo)
{
  int i = (blockIdx.x*256 + threadIdx.x)*8;
  float f[8];
  *(float4*)&f[0] = *(const float4*)&x[i];
  *(float4*)&f[4] = *(const float4*)&x[i+4];
  U8 h, l;
  #pragma unroll
  for (int j=0;j<8;++j){
    h.u[j] = f2h(f[j]);
    l.u[j] = f2h(f[j] - h2f(h.u[j]));
  }
  *(uint4*)&hi[i] = h.v;
  *(uint4*)&lo[i] = l.v;
}

__global__ __launch_bounds__(256) void conv_w(const float* __restrict__ w0, const float* __restrict__ w1,
                                              const float* __restrict__ w2, const float* __restrict__ w3,
                                              US* __restrict__ d0, US* __restrict__ d1,
                                              US* __restrict__ d2, US* __restrict__ d3)
{
  const float* s; US* d;
  switch (blockIdx.y) {
    case 0: s=w0; d=d0; break;
    case 1: s=w1; d=d1; break;
    case 2: s=w2; d=d2; break;
    default: s=w3; d=d3; break;
  }
  int i = (blockIdx.x*256 + threadIdx.x)*8;
  float f[8];
  *(float4*)&f[0] = *(const float4*)&s[i];
  *(float4*)&f[4] = *(const float4*)&s[i+4];
  U8 h;
  #pragma unroll
  for (int j=0;j<8;++j) h.u[j] = f2h(f[j]);
  *(uint4*)&d[i] = h.v;
}

// ---- GEMM: C = A @ W^T + bias.  A = A0 (+A1 residual if TERMS==2), fp16 [4096x1024].
// W fp16 [1024x1024] row-major [out][in].
// OUT 0: fp16, layout [B,H,N,D]   (Q, K, V)
// OUT 1: fp32, row-major [4096][1024]  (final)
#define LSTR 40   // 32 + 8 pad
template<int TERMS, int OUT>
__global__ __launch_bounds__(256,4) void gemm_bt(
    const US* __restrict__ A0, const US* __restrict__ A1, const US* __restrict__ W,
    const float* __restrict__ bias, void* __restrict__ out)
{
  __shared__ __align__(16) US sA0[64*LSTR];
  __shared__ __align__(16) US sA1[(TERMS==2)?64*LSTR:8];
  __shared__ __align__(16) US sW[64*LSTR];
  const int t = threadIdx.x;
  const int gm0 = blockIdx.y*64, gn0 = blockIdx.x*64;
  const int w = t>>6, lane = t&63;
  const int wr = w>>1, wc = w&1;           // 2x2 waves, each 32x32
  const int q = lane>>4, c = lane&15;
  const int lm = t>>2, kg = (t&3)*8;       // staging: 4 thr/row, 8 elems each
  const int ko = q*8;
  f32x4 acc[2][2] = {};
  for (int kb = 0; kb < 1024; kb += 32) {
    *(uint4*)&sA0[lm*LSTR+kg] = *(const uint4*)&A0[(gm0+lm)*1024 + kb + kg];
    if (TERMS==2)
      *(uint4*)&sA1[lm*LSTR+kg] = *(const uint4*)&A1[(gm0+lm)*1024 + kb + kg];
    *(uint4*)&sW[lm*LSTR+kg] = *(const uint4*)&W[(gn0+lm)*1024 + kb + kg];
    __syncthreads();
    h16x8 a0 = *(const h16x8*)&sA0[(wr*32+c)*LSTR + ko];
    h16x8 a1 = *(const h16x8*)&sA0[(wr*32+16+c)*LSTR + ko];
    h16x8 b0 = *(const h16x8*)&sW[(wc*32+c)*LSTR + ko];
    h16x8 b1 = *(const h16x8*)&sW[(wc*32+16+c)*LSTR + ko];
    acc[0][0] = MFMA16F(a0,b0,acc[0][0]);
    acc[0][1] = MFMA16F(a0,b1,acc[0][1]);
    acc[1][0] = MFMA16F(a1,b0,acc[1][0]);
    acc[1][1] = MFMA16F(a1,b1,acc[1][1]);
    if (TERMS==2) {
      h16x8 a0l = *(const h16x8*)&sA1[(wr*32+c)*LSTR + ko];
      h16x8 a1l = *(const h16x8*)&sA1[(wr*32+16+c)*LSTR + ko];
      acc[0][0] = MFMA16F(a0l,b0,acc[0][0]);
      acc[0][1] = MFMA16F(a0l,b1,acc[0][1]);
      acc[1][0] = MFMA16F(a1l,b0,acc[1][0]);
      acc[1][1] = MFMA16F(a1l,b1,acc[1][1]);
    }
    __syncthreads();
  }
  #pragma unroll
  for (int f=0; f<2; ++f)
  #pragma unroll
  for (int g=0; g<2; ++g) {
    int col = gn0 + wc*32 + g*16 + c;
    float bv = bias[col];
    #pragma unroll
    for (int r=0; r<4; ++r) {
      int row = gm0 + wr*32 + f*16 + q*4 + r;   // C layout: row=(lane>>4)*4+reg, col=lane&15
      float v = acc[f][g][r] + bv;
      if (OUT == 1) {
        ((float*)out)[row*1024 + col] = v;
      } else {
        int b = row>>11, n = row & (N_-1), hh = col>>6, d = col & 63;
        ((US*)out)[((b*H_+hh)*N_+n)*D_ + d] = f2h(v);
      }
    }
  }
}

// ---- Flash attention, all fp16. One block = one (b,h) x 64 q-rows; wave w owns rows 16w..16w+15.
// Q frags live in registers (direct global load); K tile + V^T tile + per-wave P in LDS.
#define ASTR 72   // 64 + 8 pad
__global__ __launch_bounds__(256,4) void attn(
    const US* __restrict__ Qf, const US* __restrict__ Kf, const US* __restrict__ Vf,
    US* __restrict__ Hout)
{
  __shared__ __align__(16) US sK[64*ASTR];
  __shared__ __align__(16) US sVt[64*ASTR];     // transposed V tile [d][m]
  __shared__ __align__(16) US sP[4][16*ASTR];   // per-wave P buffer
  const int t = threadIdx.x;
  const int w = t>>6, lane = t&63, q = lane>>4, c = lane&15;
  const int bh = blockIdx.y;          // b*16 + h
  const int n0 = blockIdx.x*64;
  const int base = bh * (N_*D_);
  const US* Kp = Kf + base;
  const US* Vv = Vf + base;

  // Q A-frags straight from global (one-time): row = n0 + w*16 + c, k-chunks q*8 and 32+q*8
  const int ar = w*16 + c;
  h16x8 qa0 = *(const h16x8*)&Qf[base + (n0+ar)*D_ + q*8];
  h16x8 qa1 = *(const h16x8*)&Qf[base + (n0+ar)*D_ + 32 + q*8];

  float mi[4], li[4];
  f32x4 o[4];
  #pragma unroll
  for (int r=0;r<4;++r){ mi[r] = -INFINITY; li[r] = 0.f; f32x4 z = {}; o[r] = z; }

  const int sr = t>>3, sk = (t&7)*8;  // K staging: 8 thr/row, 8 fp16 each
  const int pr = t>>3;                // V-transpose pair index 0..31
  const int d0 = (t&7)*8;

  for (int mt=0; mt<32; ++mt) {
    const int m0 = mt*64;
    #pragma unroll
    for (int p=0;p<2;p++){
      int m = sr + 32*p;
      *(uint4*)&sK[m*ASTR+sk] = *(const uint4*)&Kp[(m0+m)*D_ + sk];
    }
    { // stage V transposed: sVt[d][m], pack 2 m's per b32 write
      uint4 va = *(const uint4*)&Vv[(m0+2*pr)*D_ + d0];
      uint4 vb = *(const uint4*)&Vv[(m0+2*pr+1)*D_ + d0];
      const US* pa = (const US*)&va; const US* pb = (const US*)&vb;
      int rot = (d0>>3)&7;            // stagger to avoid bank aliasing
      #pragma unroll
      for (int jj=0;jj<8;++jj){
        int j = (jj + rot)&7;
        unsigned pack = (unsigned)pa[j] | ((unsigned)pb[j]<<16);
        *(unsigned*)&sVt[(d0+j)*ASTR + 2*pr] = pack;
      }
    }
    __syncthreads();

    // S tile: 16 q-rows x 64 m-cols
    f32x4 s[4];
    #pragma unroll
    for (int j=0;j<4;++j){
      int br = j*16 + c;
      h16x8 b0 = *(const h16x8*)&sK[br*ASTR + q*8];
      h16x8 b1 = *(const h16x8*)&sK[br*ASTR + 32 + q*8];
      f32x4 sv = {};
      sv = MFMA16F(qa0,b0,sv);
      sv = MFMA16F(qa1,b1,sv);
      s[j] = sv;
    }
    #pragma unroll
    for (int j=0;j<4;++j) s[j] *= 8.0f;   // logits = dot * sqrt(D)

    // online softmax: rows live in quads (row = q*4+r), reduce over 16 lanes
    float alpha[4];
    #pragma unroll
    for (int r=0;r<4;++r){
      float v = fmaxf(fmaxf(s[0][r],s[1][r]), fmaxf(s[2][r],s[3][r]));
      v = fmaxf(v, __shfl_xor(v,1));
      v = fmaxf(v, __shfl_xor(v,2));
      v = fmaxf(v, __shfl_xor(v,4));
      v = fmaxf(v, __shfl_xor(v,8));
      float mnew = fmaxf(mi[r], v);
      alpha[r] = __expf(mi[r]-mnew);
      mi[r] = mnew;
      float ps = 0.f;
      #pragma unroll
      for (int j=0;j<4;++j){
        float p = __expf(s[j][r]-mnew);
        s[j][r] = p;
        ps += p;
      }
      ps += __shfl_xor(ps,1);
      ps += __shfl_xor(ps,2);
      ps += __shfl_xor(ps,4);
      ps += __shfl_xor(ps,8);
      li[r] = li[r]*alpha[r] + ps;
    }
    #pragma unroll
    for (int dt=0;dt<4;++dt){
      #pragma unroll
      for (int r=0;r<4;++r) o[dt][r] *= alpha[r];
    }
    // P: C-layout regs -> LDS -> A-layout frags (per-wave buffer)
    #pragma unroll
    for (int j=0;j<4;++j)
      #pragma unroll
      for (int r=0;r<4;++r)
        sP[w][(q*4+r)*ASTR + j*16 + c] = f2h(s[j][r]);
    h16x8 pa0 = *(const h16x8*)&sP[w][c*ASTR + q*8];
    h16x8 pa1 = *(const h16x8*)&sP[w][c*ASTR + 32 + q*8];
    #pragma unroll
    for (int dt=0;dt<4;++dt){
      h16x8 vb0 = *(const h16x8*)&sVt[(dt*16+c)*ASTR + q*8];
      h16x8 vb1 = *(const h16x8*)&sVt[(dt*16+c)*ASTR + 32 + q*8];
      o[dt] = MFMA16F(pa0, vb0, o[dt]);
      o[dt] = MFMA16F(pa1, vb1, o[dt]);
    }
    __syncthreads();
  }
  const int b = bh>>4, hh = bh&15;
  #pragma unroll
  for (int dt=0;dt<4;++dt){
    #pragma unroll
    for (int r=0;r<4;++r){
      int n = n0 + w*16 + q*4 + r;
      int d = dt*16 + c;
      float val = o[dt][r] / li[r];
      Hout[((b*N_+n)*H_+hh)*D_ + d] = f2h(val);   // [B,N,E] row-major, fp16
    }
  }
}

extern "C" void kernel_launch(void* const* d_in, const int* in_sizes, int n_in,
                              void* d_out, int out_size, void* d_ws, size_t ws_size,
                              hipStream_t stream)
{
  const float* x  = (const float*)d_in[0];
  const float* Wq = (const float*)d_in[1];
  const float* bq = (const float*)d_in[2];
  const float* Wk = (const float*)d_in[3];
  const float* bk = (const float*)d_in[4];
  const float* Wv = (const float*)d_in[5];
  const float* bv = (const float*)d_in[6];
  const float* Wo = (const float*)d_in[7];
  const float* bo = (const float*)d_in[8];
  US* ws  = (US*)d_ws;
  US* xh  = ws;                           // 4M
  US* xl  = ws + (size_t)4*1048576;       // 4M
  US* Wqf = ws + (size_t)8*1048576;       // 1M
  US* Wkf = ws + (size_t)9*1048576;       // 1M
  US* Wvf = ws + (size_t)10*1048576;      // 1M
  US* Wof = ws + (size_t)11*1048576;      // 1M
  US* Qf  = ws + (size_t)12*1048576;      // 4M
  US* Kf  = ws + (size_t)16*1048576;      // 4M -> total 40 MB
  US* Vf  = xl;   // xl dead after gemm K
  US* Hf  = xh;   // xh dead after gemm V

  conv_x<<<2048, 256, 0, stream>>>(x, xh, xl);
  conv_w<<<dim3(512,4,1), 256, 0, stream>>>(Wq, Wk, Wv, Wo, Wqf, Wkf, Wvf, Wof);

  dim3 gg(16, 64), bb(256, 1, 1);
  gemm_bt<2,0><<<gg, bb, 0, stream>>>(xh, xl, Wqf, bq, Qf);
  gemm_bt<2,0><<<gg, bb, 0, stream>>>(xh, xl, Wkf, bk, Kf);
  gemm_bt<1,0><<<gg, bb, 0, stream>>>(xh, nullptr, Wvf, bv, Vf);
  attn<<<dim3(32,32,1), bb, 0, stream>>>(Qf, Kf, Vf, Hf);
  gemm_bt<1,1><<<gg, bb, 0, stream>>>(Hf, nullptr, Wof, bo, d_out);
}